// Round 1
// 1304.289 us; speedup vs baseline: 1.8742x; 1.8742x over previous
//
#include <hip/hip_runtime.h>
#include <math.h>

// WaveNet residual block, MFMA version (split-bf16 "bf16x3" emulation of fp32 GEMM).
// B=32, C=128, T=16000, K=2, dilation=2 (hardcoded).
//
// GEMM view: f/g/skip are [co=128] x [kappa=256] x [t] GEMMs with kappa = tap*128 + ci.
//   f/g taps:  B[kappa][m] = x[ci][ts-1+m - 2 + 2*tap]   (o col m <-> time ts-1+m, m=0..63)
//   skip taps: B[kappa][n] = o[ci][ts+n  - 1 +   tap]    (out col n = jj, jj=0..62 stored)
// A operand (weights) pre-converted to kappa-major bf16 hi/lo planes in d_ws by prep kernel.
// Each value v = hi + lo (bf16 pair); GEMM = Ah*Bh + Ah*Bl + Al*Bh, fp32 accum -> ~2^-17 rel err.
//
// Per block: batch b, 63 output cols. 4 waves; wave w owns co rows [w*32, w*32+32), all 64 cols.
// mfma_f32_16x16x32_bf16: A row = lane&15, k = (lane>>4)*8+j ; B col = lane&15, same k ;
// D col = lane&15, row = (lane>>4)*4 + reg   [m89-verified mapping].

#define CCH 128
#define TLEN 16000
#define NB 32
#define TT 63        // output cols per block
#define XC 66        // x halo cols: [ts-3, ts+62]
#define XTP 136      // LDS row pad: 128+8 bf16 -> 272B row stride (offset-4-banks per row)
#define XSTRIDE 68   // (fallback fp32 kernel)
#define OSTRIDE 68

typedef __attribute__((ext_vector_type(8))) short bf16x8;
typedef __attribute__((ext_vector_type(4))) float f32x4;

__device__ __forceinline__ unsigned short f2bf(float f) {
    union { float f; unsigned u; } v; v.f = f;
    unsigned u = v.u + 0x7FFFu + ((v.u >> 16) & 1u);   // RNE
    return (unsigned short)(u >> 16);
}
__device__ __forceinline__ float bf2f(unsigned short h) {
    union { float f; unsigned u; } v; v.u = ((unsigned)h) << 16;
    return v.f;
}

// ---------------- weight prep: fp32 [co][ci][k] -> bf16 hi/lo planes [co][kappa] ----------------
// plane order: f_hi, f_lo, g_hi, g_lo, s_hi, s_lo ; plane = 128*256 bf16 = 64KB ; total 384KB.
__global__ void prep_weights(const float* __restrict__ wf,
                             const float* __restrict__ wg,
                             const float* __restrict__ wsk,
                             unsigned short* __restrict__ wp)
{
    int idx = blockIdx.x * 256 + threadIdx.x;
    if (idx >= 3 * CCH * 256) return;
    int m   = idx >> 15;        // which matrix
    int rem = idx & 32767;      // co*256 + kappa
    int co  = rem >> 8;
    int kap = rem & 255;
    int tp = kap >> 7, ci = kap & 127;
    const float* w = (m == 0) ? wf : (m == 1) ? wg : wsk;
    float v = w[((size_t)co * CCH + ci) * 2 + tp];
    unsigned short h = f2bf(v);
    unsigned short lo = f2bf(v - bf2f(h));
    wp[(size_t)(2 * m)     * 32768 + rem] = h;
    wp[(size_t)(2 * m + 1) * 32768 + rem] = lo;
}

// ---------------- main fused kernel ----------------
__global__ __launch_bounds__(256, 2)
void wavenet_mfma(const float* __restrict__ x,
                  const unsigned short* __restrict__ wp,
                  float* __restrict__ out,
                  float* __restrict__ skip)
{
    __shared__ unsigned short xTh[XC][XTP];   // x hi, row c <-> time ts-3+c, col = ci
    __shared__ unsigned short xTl[XC][XTP];   // x lo
    __shared__ unsigned short oTh[65][XTP];   // o hi, row m <-> time ts-1+m (row 64 = zeros)
    __shared__ unsigned short oTl[65][XTP];   // o lo

    const int b   = blockIdx.y;
    const int ts  = blockIdx.x * TT;
    const int tid = threadIdx.x;

    // phase 0: stage x tile, transposed, split hi/lo
    const float* xb = x + (size_t)b * CCH * TLEN;
    for (int i = tid; i < CCH * XC; i += 256) {
        int ci = i / XC, c = i - ci * XC;
        int t = ts - 3 + c;
        float v = (t >= 0 && t < TLEN) ? xb[ci * TLEN + t] : 0.f;
        unsigned short h = f2bf(v);
        xTh[c][ci] = h;
        xTl[c][ci] = f2bf(v - bf2f(h));
    }
    if (tid < CCH) { oTh[64][tid] = 0; oTl[64][tid] = 0; }
    __syncthreads();

    const int l   = tid & 63;
    const int wv  = tid >> 6;
    const int li  = l & 15;     // A row / B,D col within 16-tile
    const int lg  = l >> 4;     // k-group (k = lg*8 + j), D row group
    const int coB = wv * 32;

    const unsigned short* Wfh = wp;
    const unsigned short* Wfl = wp + 32768;
    const unsigned short* Wgh = wp + 2 * 32768;
    const unsigned short* Wgl = wp + 3 * 32768;
    const unsigned short* Wsh = wp + 4 * 32768;
    const unsigned short* Wsl = wp + 5 * 32768;

    // ---------------- phase 1: f/g GEMM (K=256 in 8 chunks of 32) ----------------
    f32x4 accf[2][4], accg[2][4];
    #pragma unroll
    for (int rt = 0; rt < 2; ++rt)
        #pragma unroll
        for (int ct = 0; ct < 4; ++ct) {
            accf[rt][ct] = (f32x4){0.f, 0.f, 0.f, 0.f};
            accg[rt][ct] = (f32x4){0.f, 0.f, 0.f, 0.f};
        }

    for (int kc = 0; kc < 8; ++kc) {
        const int tp   = kc >> 2;                    // kappa chunks 0-3: tap0, 4-7: tap1
        const int ciq  = ((kc & 3) * 32) + lg * 8;   // ci base of this lane's 8 k-elems
        const int kap0 = kc * 32 + lg * 8;
        bf16x8 afh[2], afl[2], agh[2], agl[2];
        #pragma unroll
        for (int rt = 0; rt < 2; ++rt) {
            const int off = (coB + rt * 16 + li) * 256 + kap0;
            afh[rt] = *(const bf16x8*)(Wfh + off);
            afl[rt] = *(const bf16x8*)(Wfl + off);
            agh[rt] = *(const bf16x8*)(Wgh + off);
            agl[rt] = *(const bf16x8*)(Wgl + off);
        }
        #pragma unroll
        for (int ct = 0; ct < 4; ++ct) {
            const int row = ct * 16 + li + 2 * tp;   // m + 2*tap, max 65
            bf16x8 bh = *(const bf16x8*)&xTh[row][ciq];
            bf16x8 bl = *(const bf16x8*)&xTl[row][ciq];
            #pragma unroll
            for (int rt = 0; rt < 2; ++rt) {
                accf[rt][ct] = __builtin_amdgcn_mfma_f32_16x16x32_bf16(afh[rt], bh, accf[rt][ct], 0, 0, 0);
                accf[rt][ct] = __builtin_amdgcn_mfma_f32_16x16x32_bf16(afh[rt], bl, accf[rt][ct], 0, 0, 0);
                accf[rt][ct] = __builtin_amdgcn_mfma_f32_16x16x32_bf16(afl[rt], bh, accf[rt][ct], 0, 0, 0);
                accg[rt][ct] = __builtin_amdgcn_mfma_f32_16x16x32_bf16(agh[rt], bh, accg[rt][ct], 0, 0, 0);
                accg[rt][ct] = __builtin_amdgcn_mfma_f32_16x16x32_bf16(agh[rt], bl, accg[rt][ct], 0, 0, 0);
                accg[rt][ct] = __builtin_amdgcn_mfma_f32_16x16x32_bf16(agl[rt], bh, accg[rt][ct], 0, 0, 0);
            }
        }
    }

    // gated activation (same numerics as fp32 kernel) -> oT hi/lo
    #pragma unroll
    for (int rt = 0; rt < 2; ++rt)
        #pragma unroll
        for (int ct = 0; ct < 4; ++ct)
            #pragma unroll
            for (int r = 0; r < 4; ++r) {
                const float f = accf[rt][ct][r], g = accg[rt][ct][r];
                const float e2 = __expf(-2.f * f);
                const float th = (1.f - e2) / (1.f + e2);    // tanh(f)
                const float sg = 1.f / (1.f + __expf(-g));   // sigmoid(g)
                const float o = th * sg;
                const int co = coB + rt * 16 + lg * 4 + r;   // D row
                const int m  = ct * 16 + li;                 // D col
                unsigned short h = f2bf(o);
                oTh[m][co] = h;
                oTl[m][co] = f2bf(o - bf2f(h));
            }
    __syncthreads();

    // ---------------- phase 2: skip GEMM ----------------
    f32x4 accs[2][4];
    #pragma unroll
    for (int rt = 0; rt < 2; ++rt)
        #pragma unroll
        for (int ct = 0; ct < 4; ++ct)
            accs[rt][ct] = (f32x4){0.f, 0.f, 0.f, 0.f};

    for (int kc = 0; kc < 8; ++kc) {
        const int tp   = kc >> 2;
        const int ciq  = ((kc & 3) * 32) + lg * 8;
        const int kap0 = kc * 32 + lg * 8;
        bf16x8 ash[2], asl[2];
        #pragma unroll
        for (int rt = 0; rt < 2; ++rt) {
            const int off = (coB + rt * 16 + li) * 256 + kap0;
            ash[rt] = *(const bf16x8*)(Wsh + off);
            asl[rt] = *(const bf16x8*)(Wsl + off);
        }
        #pragma unroll
        for (int ct = 0; ct < 4; ++ct) {
            const int row = ct * 16 + li + tp;   // jj + tap, max 64 (row 64 = zeros, col dropped)
            bf16x8 bh = *(const bf16x8*)&oTh[row][ciq];
            bf16x8 bl = *(const bf16x8*)&oTl[row][ciq];
            #pragma unroll
            for (int rt = 0; rt < 2; ++rt) {
                accs[rt][ct] = __builtin_amdgcn_mfma_f32_16x16x32_bf16(ash[rt], bh, accs[rt][ct], 0, 0, 0);
                accs[rt][ct] = __builtin_amdgcn_mfma_f32_16x16x32_bf16(ash[rt], bl, accs[rt][ct], 0, 0, 0);
                accs[rt][ct] = __builtin_amdgcn_mfma_f32_16x16x32_bf16(asl[rt], bh, accs[rt][ct], 0, 0, 0);
            }
        }
    }

    // epilogue: out = skip + x (x reconstructed hi+lo, err ~2^-17)
    float* outb = out  + (size_t)b * CCH * TLEN;
    float* skb  = skip + (size_t)b * CCH * TLEN;
    #pragma unroll
    for (int rt = 0; rt < 2; ++rt)
        #pragma unroll
        for (int ct = 0; ct < 4; ++ct)
            #pragma unroll
            for (int r = 0; r < 4; ++r) {
                const int co = coB + rt * 16 + lg * 4 + r;
                const int jj = ct * 16 + li;         // output col within tile
                const int t  = ts + jj;
                if (jj < TT && t < TLEN) {
                    const float s = accs[rt][ct][r];
                    const float xv = bf2f(xTh[jj + 3][co]) + bf2f(xTl[jj + 3][co]);
                    outb[(size_t)co * TLEN + t] = s + xv;
                    skb [(size_t)co * TLEN + t] = s;
                }
            }
}

// ---------------- fallback: previous fp32 kernel (used only if ws too small) ----------------
__global__ __launch_bounds__(256, 2)
void wavenet_fused_f32(const float* __restrict__ x,
                       const float* __restrict__ wf,
                       const float* __restrict__ wg,
                       const float* __restrict__ wsk,
                       float* __restrict__ out,
                       float* __restrict__ skip)
{
    __shared__ float xs[CCH][XSTRIDE];
    __shared__ float os[CCH][OSTRIDE];

    const int b  = blockIdx.y;
    const int ts = blockIdx.x * TT;
    const int tid = threadIdx.x;

    const float* xb = x + (size_t)b * CCH * TLEN;
    for (int i = tid; i < CCH * XC; i += 256) {
        const int ch = i / XC, col = i % XC;
        const int t = ts - 3 + col;
        float v = 0.f;
        if (t >= 0 && t < TLEN) v = xb[ch * TLEN + t];
        xs[ch][col] = v;
    }
    __syncthreads();

    const int tg  = tid & 15;
    const int cg  = tid >> 4;
    const int tl  = tg * 4;
    const int co0 = cg * 8;

    float ff[8][4], gg[8][4];
    #pragma unroll
    for (int c = 0; c < 8; ++c)
        #pragma unroll
        for (int j = 0; j < 4; ++j) { ff[c][j] = 0.f; gg[c][j] = 0.f; }

    for (int ci = 0; ci < CCH; ci += 2) {
        const float4 a0 = *(const float4*)&xs[ci][tl];
        const float4 a1 = *(const float4*)&xs[ci][tl + 4];
        const float4 b0 = *(const float4*)&xs[ci + 1][tl];
        const float4 b1 = *(const float4*)&xs[ci + 1][tl + 4];
        const float t0a[4] = {a0.x, a0.y, a0.z, a0.w};
        const float t1a[4] = {a0.z, a0.w, a1.x, a1.y};
        const float t0b[4] = {b0.x, b0.y, b0.z, b0.w};
        const float t1b[4] = {b0.z, b0.w, b1.x, b1.y};
        #pragma unroll
        for (int c = 0; c < 8; ++c) {
            const float4 w4f = *(const float4*)&wf[((size_t)(co0 + c) * CCH + ci) * 2];
            const float4 w4g = *(const float4*)&wg[((size_t)(co0 + c) * CCH + ci) * 2];
            #pragma unroll
            for (int j = 0; j < 4; ++j) {
                ff[c][j] = fmaf(w4f.x, t0a[j], ff[c][j]);
                ff[c][j] = fmaf(w4f.y, t1a[j], ff[c][j]);
                ff[c][j] = fmaf(w4f.z, t0b[j], ff[c][j]);
                ff[c][j] = fmaf(w4f.w, t1b[j], ff[c][j]);
                gg[c][j] = fmaf(w4g.x, t0a[j], gg[c][j]);
                gg[c][j] = fmaf(w4g.y, t1a[j], gg[c][j]);
                gg[c][j] = fmaf(w4g.z, t0b[j], gg[c][j]);
                gg[c][j] = fmaf(w4g.w, t1b[j], gg[c][j]);
            }
        }
    }

    #pragma unroll
    for (int c = 0; c < 8; ++c) {
        float4 ov;
        float* po = (float*)&ov;
        #pragma unroll
        for (int j = 0; j < 4; ++j) {
            const float f = ff[c][j], g = gg[c][j];
            const float e2 = __expf(-2.f * f);
            const float th = (1.f - e2) / (1.f + e2);
            const float sg = 1.f / (1.f + __expf(-g));
            po[j] = th * sg;
        }
        *(float4*)&os[co0 + c][tl] = ov;
    }
    __syncthreads();

    float sk[8][4];
    #pragma unroll
    for (int c = 0; c < 8; ++c)
        #pragma unroll
        for (int j = 0; j < 4; ++j) sk[c][j] = 0.f;

    for (int ci = 0; ci < CCH; ci += 2) {
        const float4 a0 = *(const float4*)&os[ci][tl];
        const float4 a1 = *(const float4*)&os[ci][tl + 4];
        const float4 b0 = *(const float4*)&os[ci + 1][tl];
        const float4 b1 = *(const float4*)&os[ci + 1][tl + 4];
        const float t0a[4] = {a0.x, a0.y, a0.z, a0.w};
        const float t1a[4] = {a0.y, a0.z, a0.w, a1.x};
        const float t0b[4] = {b0.x, b0.y, b0.z, b0.w};
        const float t1b[4] = {b0.y, b0.z, b0.w, b1.x};
        #pragma unroll
        for (int c = 0; c < 8; ++c) {
            const float4 w4s = *(const float4*)&wsk[((size_t)(co0 + c) * CCH + ci) * 2];
            #pragma unroll
            for (int j = 0; j < 4; ++j) {
                sk[c][j] = fmaf(w4s.x, t0a[j], sk[c][j]);
                sk[c][j] = fmaf(w4s.y, t1a[j], sk[c][j]);
                sk[c][j] = fmaf(w4s.z, t0b[j], sk[c][j]);
                sk[c][j] = fmaf(w4s.w, t1b[j], sk[c][j]);
            }
        }
    }

    float* outb = out  + (size_t)b * CCH * TLEN;
    float* skb  = skip + (size_t)b * CCH * TLEN;
    #pragma unroll
    for (int c = 0; c < 8; ++c) {
        #pragma unroll
        for (int j = 0; j < 4; ++j) {
            const int jj = tl + j;
            const int t  = ts + jj;
            if (jj < TT && t < TLEN) {
                const float s = sk[c][j];
                outb[(size_t)(co0 + c) * TLEN + t] = s + xs[co0 + c][jj + 3];
                skb [(size_t)(co0 + c) * TLEN + t] = s;
            }
        }
    }
}

extern "C" void kernel_launch(void* const* d_in, const int* in_sizes, int n_in,
                              void* d_out, int out_size, void* d_ws, size_t ws_size,
                              hipStream_t stream) {
    const float* x   = (const float*)d_in[0];
    const float* wf  = (const float*)d_in[1];
    const float* wg  = (const float*)d_in[2];
    const float* wsk = (const float*)d_in[3];
    // d_in[4] = dilation (=2, hardcoded)

    float* out  = (float*)d_out;
    float* skip = out + (size_t)NB * CCH * TLEN;

    dim3 grid((TLEN + TT - 1) / TT, NB);  // 254 x 32

    const size_t ws_needed = (size_t)6 * 32768 * sizeof(unsigned short);  // 384 KB
    if (ws_size < ws_needed) {
        wavenet_fused_f32<<<grid, 256, 0, stream>>>(x, wf, wg, wsk, out, skip);
        return;
    }

    unsigned short* wp = (unsigned short*)d_ws;
    prep_weights<<<dim3(384), 256, 0, stream>>>(wf, wg, wsk, wp);
    wavenet_mfma<<<grid, 256, 0, stream>>>(x, wp, out, skip);
}

// Round 2
// 1205.444 us; speedup vs baseline: 2.0279x; 1.0820x over previous
//
#include <hip/hip_runtime.h>
#include <math.h>

// WaveNet residual block, MFMA version (split-bf16 "bf16x3" emulation of fp32 GEMM).
// B=32, C=128, T=16000, K=2, dilation=2 (hardcoded).
//
// GEMM view: f/g/skip are [co=128] x [kappa=256] x [t] GEMMs with kappa = tap*128 + ci.
//   f/g taps:  B[kappa][m] = x[ci][ts-1+m - 2 + 2*tap]   (o col m <-> time ts-1+m, m=0..63)
//   skip taps: B[kappa][n] = o[ci][ts+n  - 1 +   tap]    (out col n = jj, jj=0..62 stored)
// Weights pre-converted to kappa-major bf16 hi/lo planes in d_ws. v = hi + lo;
// GEMM = Ah*Bh + Ah*Bl + Al*Bh, fp32 accum -> ~2^-17 rel err.
//
// R2 change: oT tile ALIASES the xT tile (disjoint live ranges; extra barrier) ->
// LDS 70KB -> 36KB -> 4 blocks/CU (launch_bounds(256,4)). Residual now re-read
// from global (L2-hot, exact fp32). One fused divide in the activation.
//
// mfma_f32_16x16x32_bf16: A row = lane&15, k = (lane>>4)*8+j ; B col = lane&15 ;
// D col = lane&15, row = (lane>>4)*4 + reg   [m89-verified mapping].

#define CCH 128
#define TLEN 16000
#define NB 32
#define TT 63        // output cols per block
#define XC 66        // x halo rows: time ts-3 .. ts+62 ; o rows 0..64 reuse same buffer
#define XTP 136      // LDS row pad: 128+8 shorts -> 272B row stride (16B-aligned rows)
#define XSTRIDE 68   // (fallback fp32 kernel)
#define OSTRIDE 68

typedef __attribute__((ext_vector_type(8))) short bf16x8;
typedef __attribute__((ext_vector_type(4))) float f32x4;

__device__ __forceinline__ unsigned short f2bf(float f) {
    union { float f; unsigned u; } v; v.f = f;
    unsigned u = v.u + 0x7FFFu + ((v.u >> 16) & 1u);   // RNE
    return (unsigned short)(u >> 16);
}
__device__ __forceinline__ float bf2f(unsigned short h) {
    union { float f; unsigned u; } v; v.u = ((unsigned)h) << 16;
    return v.f;
}

// ---------------- weight prep: fp32 [co][ci][k] -> bf16 hi/lo planes [co][kappa] ----------------
// plane order: f_hi, f_lo, g_hi, g_lo, s_hi, s_lo ; plane = 128*256 bf16 = 64KB ; total 384KB.
__global__ void prep_weights(const float* __restrict__ wf,
                             const float* __restrict__ wg,
                             const float* __restrict__ wsk,
                             unsigned short* __restrict__ wp)
{
    int idx = blockIdx.x * 256 + threadIdx.x;
    if (idx >= 3 * CCH * 256) return;
    int m   = idx >> 15;        // which matrix
    int rem = idx & 32767;      // co*256 + kappa
    int co  = rem >> 8;
    int kap = rem & 255;
    int tp = kap >> 7, ci = kap & 127;
    const float* w = (m == 0) ? wf : (m == 1) ? wg : wsk;
    float v = w[((size_t)co * CCH + ci) * 2 + tp];
    unsigned short h = f2bf(v);
    unsigned short lo = f2bf(v - bf2f(h));
    wp[(size_t)(2 * m)     * 32768 + rem] = h;
    wp[(size_t)(2 * m + 1) * 32768 + rem] = lo;
}

// ---------------- main fused kernel ----------------
__global__ __launch_bounds__(256, 4)
void wavenet_mfma(const float* __restrict__ x,
                  const unsigned short* __restrict__ wp,
                  float* __restrict__ out,
                  float* __restrict__ skip)
{
    // Shared tile, hi/lo planes. Holds x (rows 0..65 <-> time ts-3+row) in phase 1,
    // then o (rows 0..63 <-> time ts-1+row, row 64 = zeros) in phase 2.
    __shared__ unsigned short sh[2][XC][XTP];

    const int b   = blockIdx.y;
    const int ts  = blockIdx.x * TT;
    const int tid = threadIdx.x;

    // ---------------- phase 0: stage x tile, transposed, split hi/lo ----------------
    const float* xb = x + (size_t)b * CCH * TLEN;
    for (int k = 0; k < 33; ++k) {             // 33*256 == 128*66 exactly
        int i = tid + k * 256;
        int ci = i / XC, c = i - ci * XC;
        int t = ts - 3 + c;
        float v = (t >= 0 && t < TLEN) ? xb[ci * TLEN + t] : 0.f;
        unsigned short h = f2bf(v);
        sh[0][c][ci] = h;
        sh[1][c][ci] = f2bf(v - bf2f(h));
    }
    __syncthreads();

    const int l   = tid & 63;
    const int wv  = tid >> 6;
    const int li  = l & 15;     // A row / B,D col within 16-tile
    const int lg  = l >> 4;     // k-group (k = lg*8 + j), D row group
    const int coB = wv * 32;

    const unsigned short* Wfh = wp;
    const unsigned short* Wfl = wp + 32768;
    const unsigned short* Wgh = wp + 2 * 32768;
    const unsigned short* Wgl = wp + 3 * 32768;
    const unsigned short* Wsh = wp + 4 * 32768;
    const unsigned short* Wsl = wp + 5 * 32768;

    // ---------------- phase 1: f/g GEMM (K=256 in 8 chunks of 32) ----------------
    f32x4 accf[2][4], accg[2][4];
    #pragma unroll
    for (int rt = 0; rt < 2; ++rt)
        #pragma unroll
        for (int ct = 0; ct < 4; ++ct) {
            accf[rt][ct] = (f32x4){0.f, 0.f, 0.f, 0.f};
            accg[rt][ct] = (f32x4){0.f, 0.f, 0.f, 0.f};
        }

    for (int kc = 0; kc < 8; ++kc) {
        const int tp   = kc >> 2;                    // kappa chunks 0-3: tap0, 4-7: tap1
        const int ciq  = ((kc & 3) * 32) + lg * 8;   // ci base of this lane's 8 k-elems
        const int kap0 = kc * 32 + lg * 8;
        bf16x8 afh[2], afl[2], agh[2], agl[2];
        #pragma unroll
        for (int rt = 0; rt < 2; ++rt) {
            const int off = (coB + rt * 16 + li) * 256 + kap0;
            afh[rt] = *(const bf16x8*)(Wfh + off);
            afl[rt] = *(const bf16x8*)(Wfl + off);
            agh[rt] = *(const bf16x8*)(Wgh + off);
            agl[rt] = *(const bf16x8*)(Wgl + off);
        }
        #pragma unroll
        for (int ct = 0; ct < 4; ++ct) {
            const int row = ct * 16 + li + 2 * tp;   // m + 2*tap, max 65
            bf16x8 bh = *(const bf16x8*)&sh[0][row][ciq];
            bf16x8 bl = *(const bf16x8*)&sh[1][row][ciq];
            #pragma unroll
            for (int rt = 0; rt < 2; ++rt) {
                accf[rt][ct] = __builtin_amdgcn_mfma_f32_16x16x32_bf16(afh[rt], bh, accf[rt][ct], 0, 0, 0);
                accf[rt][ct] = __builtin_amdgcn_mfma_f32_16x16x32_bf16(afh[rt], bl, accf[rt][ct], 0, 0, 0);
                accf[rt][ct] = __builtin_amdgcn_mfma_f32_16x16x32_bf16(afl[rt], bh, accf[rt][ct], 0, 0, 0);
                accg[rt][ct] = __builtin_amdgcn_mfma_f32_16x16x32_bf16(agh[rt], bh, accg[rt][ct], 0, 0, 0);
                accg[rt][ct] = __builtin_amdgcn_mfma_f32_16x16x32_bf16(agh[rt], bl, accg[rt][ct], 0, 0, 0);
                accg[rt][ct] = __builtin_amdgcn_mfma_f32_16x16x32_bf16(agl[rt], bh, accg[rt][ct], 0, 0, 0);
            }
        }
    }

    // all waves must be done READING x before o overwrites the aliased tile
    __syncthreads();

    // gated activation (one fused divide) -> o hi/lo into aliased tile
    if (tid < CCH) { sh[0][64][tid] = 0; sh[1][64][tid] = 0; }   // o row 64 = zeros
    #pragma unroll
    for (int rt = 0; rt < 2; ++rt)
        #pragma unroll
        for (int ct = 0; ct < 4; ++ct)
            #pragma unroll
            for (int r = 0; r < 4; ++r) {
                const float f = accf[rt][ct][r], g = accg[rt][ct][r];
                const float e2 = __expf(-2.f * f);
                const float eg = __expf(-g);
                // tanh(f)*sigmoid(g) = (1-e2) / ((1+e2)*(1+eg))
                const float o = (1.f - e2) / ((1.f + e2) * (1.f + eg));
                const int co = coB + rt * 16 + lg * 4 + r;   // D row
                const int m  = ct * 16 + li;                 // D col
                unsigned short h = f2bf(o);
                sh[0][m][co] = h;
                sh[1][m][co] = f2bf(o - bf2f(h));
            }
    __syncthreads();

    // ---------------- phase 2: skip GEMM ----------------
    f32x4 accs[2][4];
    #pragma unroll
    for (int rt = 0; rt < 2; ++rt)
        #pragma unroll
        for (int ct = 0; ct < 4; ++ct)
            accs[rt][ct] = (f32x4){0.f, 0.f, 0.f, 0.f};

    for (int kc = 0; kc < 8; ++kc) {
        const int tp   = kc >> 2;
        const int ciq  = ((kc & 3) * 32) + lg * 8;
        const int kap0 = kc * 32 + lg * 8;
        bf16x8 ash[2], asl[2];
        #pragma unroll
        for (int rt = 0; rt < 2; ++rt) {
            const int off = (coB + rt * 16 + li) * 256 + kap0;
            ash[rt] = *(const bf16x8*)(Wsh + off);
            asl[rt] = *(const bf16x8*)(Wsl + off);
        }
        #pragma unroll
        for (int ct = 0; ct < 4; ++ct) {
            const int row = ct * 16 + li + tp;   // jj + tap, max 64 (row 64 = zeros, col dropped)
            bf16x8 bh = *(const bf16x8*)&sh[0][row][ciq];
            bf16x8 bl = *(const bf16x8*)&sh[1][row][ciq];
            #pragma unroll
            for (int rt = 0; rt < 2; ++rt) {
                accs[rt][ct] = __builtin_amdgcn_mfma_f32_16x16x32_bf16(ash[rt], bh, accs[rt][ct], 0, 0, 0);
                accs[rt][ct] = __builtin_amdgcn_mfma_f32_16x16x32_bf16(ash[rt], bl, accs[rt][ct], 0, 0, 0);
                accs[rt][ct] = __builtin_amdgcn_mfma_f32_16x16x32_bf16(asl[rt], bh, accs[rt][ct], 0, 0, 0);
            }
        }
    }

    // epilogue: out = skip + x (exact fp32 residual re-read from global, L2-hot)
    float* outb = out  + (size_t)b * CCH * TLEN;
    float* skb  = skip + (size_t)b * CCH * TLEN;
    #pragma unroll
    for (int rt = 0; rt < 2; ++rt)
        #pragma unroll
        for (int ct = 0; ct < 4; ++ct)
            #pragma unroll
            for (int r = 0; r < 4; ++r) {
                const int co = coB + rt * 16 + lg * 4 + r;
                const int jj = ct * 16 + li;         // output col within tile
                const int t  = ts + jj;
                if (jj < TT && t < TLEN) {
                    const float s = accs[rt][ct][r];
                    const float xv = xb[(size_t)co * TLEN + t];
                    outb[(size_t)co * TLEN + t] = s + xv;
                    skb [(size_t)co * TLEN + t] = s;
                }
            }
}

// ---------------- fallback: fp32 kernel (used only if ws too small) ----------------
__global__ __launch_bounds__(256, 2)
void wavenet_fused_f32(const float* __restrict__ x,
                       const float* __restrict__ wf,
                       const float* __restrict__ wg,
                       const float* __restrict__ wsk,
                       float* __restrict__ out,
                       float* __restrict__ skip)
{
    __shared__ float xs[CCH][XSTRIDE];
    __shared__ float os[CCH][OSTRIDE];

    const int b  = blockIdx.y;
    const int ts = blockIdx.x * TT;
    const int tid = threadIdx.x;

    const float* xb = x + (size_t)b * CCH * TLEN;
    for (int i = tid; i < CCH * XC; i += 256) {
        const int ch = i / XC, col = i % XC;
        const int t = ts - 3 + col;
        float v = 0.f;
        if (t >= 0 && t < TLEN) v = xb[ch * TLEN + t];
        xs[ch][col] = v;
    }
    __syncthreads();

    const int tg  = tid & 15;
    const int cg  = tid >> 4;
    const int tl  = tg * 4;
    const int co0 = cg * 8;

    float ff[8][4], gg[8][4];
    #pragma unroll
    for (int c = 0; c < 8; ++c)
        #pragma unroll
        for (int j = 0; j < 4; ++j) { ff[c][j] = 0.f; gg[c][j] = 0.f; }

    for (int ci = 0; ci < CCH; ci += 2) {
        const float4 a0 = *(const float4*)&xs[ci][tl];
        const float4 a1 = *(const float4*)&xs[ci][tl + 4];
        const float4 b0 = *(const float4*)&xs[ci + 1][tl];
        const float4 b1 = *(const float4*)&xs[ci + 1][tl + 4];
        const float t0a[4] = {a0.x, a0.y, a0.z, a0.w};
        const float t1a[4] = {a0.z, a0.w, a1.x, a1.y};
        const float t0b[4] = {b0.x, b0.y, b0.z, b0.w};
        const float t1b[4] = {b0.z, b0.w, b1.x, b1.y};
        #pragma unroll
        for (int c = 0; c < 8; ++c) {
            const float4 w4f = *(const float4*)&wf[((size_t)(co0 + c) * CCH + ci) * 2];
            const float4 w4g = *(const float4*)&wg[((size_t)(co0 + c) * CCH + ci) * 2];
            #pragma unroll
            for (int j = 0; j < 4; ++j) {
                ff[c][j] = fmaf(w4f.x, t0a[j], ff[c][j]);
                ff[c][j] = fmaf(w4f.y, t1a[j], ff[c][j]);
                ff[c][j] = fmaf(w4f.z, t0b[j], ff[c][j]);
                ff[c][j] = fmaf(w4f.w, t1b[j], ff[c][j]);
                gg[c][j] = fmaf(w4g.x, t0a[j], gg[c][j]);
                gg[c][j] = fmaf(w4g.y, t1a[j], gg[c][j]);
                gg[c][j] = fmaf(w4g.z, t0b[j], gg[c][j]);
                gg[c][j] = fmaf(w4g.w, t1b[j], gg[c][j]);
            }
        }
    }

    #pragma unroll
    for (int c = 0; c < 8; ++c) {
        float4 ov;
        float* po = (float*)&ov;
        #pragma unroll
        for (int j = 0; j < 4; ++j) {
            const float f = ff[c][j], g = gg[c][j];
            const float e2 = __expf(-2.f * f);
            const float th = (1.f - e2) / (1.f + e2);
            const float sg = 1.f / (1.f + __expf(-g));
            po[j] = th * sg;
        }
        *(float4*)&os[co0 + c][tl] = ov;
    }
    __syncthreads();

    float sk[8][4];
    #pragma unroll
    for (int c = 0; c < 8; ++c)
        #pragma unroll
        for (int j = 0; j < 4; ++j) sk[c][j] = 0.f;

    for (int ci = 0; ci < CCH; ci += 2) {
        const float4 a0 = *(const float4*)&os[ci][tl];
        const float4 a1 = *(const float4*)&os[ci][tl + 4];
        const float4 b0 = *(const float4*)&os[ci + 1][tl];
        const float4 b1 = *(const float4*)&os[ci + 1][tl + 4];
        const float t0a[4] = {a0.x, a0.y, a0.z, a0.w};
        const float t1a[4] = {a0.y, a0.z, a0.w, a1.x};
        const float t0b[4] = {b0.x, b0.y, b0.z, b0.w};
        const float t1b[4] = {b0.y, b0.z, b0.w, b1.x};
        #pragma unroll
        for (int c = 0; c < 8; ++c) {
            const float4 w4s = *(const float4*)&wsk[((size_t)(co0 + c) * CCH + ci) * 2];
            #pragma unroll
            for (int j = 0; j < 4; ++j) {
                sk[c][j] = fmaf(w4s.x, t0a[j], sk[c][j]);
                sk[c][j] = fmaf(w4s.y, t1a[j], sk[c][j]);
                sk[c][j] = fmaf(w4s.z, t0b[j], sk[c][j]);
                sk[c][j] = fmaf(w4s.w, t1b[j], sk[c][j]);
            }
        }
    }

    float* outb = out  + (size_t)b * CCH * TLEN;
    float* skb  = skip + (size_t)b * CCH * TLEN;
    #pragma unroll
    for (int c = 0; c < 8; ++c) {
        #pragma unroll
        for (int j = 0; j < 4; ++j) {
            const int jj = tl + j;
            const int t  = ts + jj;
            if (jj < TT && t < TLEN) {
                const float s = sk[c][j];
                outb[(size_t)(co0 + c) * TLEN + t] = s + xs[co0 + c][jj + 3];
                skb [(size_t)(co0 + c) * TLEN + t] = s;
            }
        }
    }
}

extern "C" void kernel_launch(void* const* d_in, const int* in_sizes, int n_in,
                              void* d_out, int out_size, void* d_ws, size_t ws_size,
                              hipStream_t stream) {
    const float* x   = (const float*)d_in[0];
    const float* wf  = (const float*)d_in[1];
    const float* wg  = (const float*)d_in[2];
    const float* wsk = (const float*)d_in[3];
    // d_in[4] = dilation (=2, hardcoded)

    float* out  = (float*)d_out;
    float* skip = out + (size_t)NB * CCH * TLEN;

    dim3 grid((TLEN + TT - 1) / TT, NB);  // 254 x 32

    const size_t ws_needed = (size_t)6 * 32768 * sizeof(unsigned short);  // 384 KB
    if (ws_size < ws_needed) {
        wavenet_fused_f32<<<grid, 256, 0, stream>>>(x, wf, wg, wsk, out, skip);
        return;
    }

    unsigned short* wp = (unsigned short*)d_ws;
    prep_weights<<<dim3(384), 256, 0, stream>>>(wf, wg, wsk, wp);
    wavenet_mfma<<<grid, 256, 0, stream>>>(x, wp, out, skip);
}